// Round 14
// baseline (1060.708 us; speedup 1.0000x reference)
//
#include <hip/hip_runtime.h>

// SNN forward, exact fixed-point int8 MFMA on 32x32x32 matrix cores.
// Full-T decoupled structure: per layer ONE batched GEMM (M=25600) -> exact
// fp64 cur -> ONE leaky-IF kernel (state in regs across all 50 steps).
// This round: gemm32w (L1/L2) LDS double-buffer, ONE barrier per k-iter;
// if_update zeroes spike K-tails (memset launch dropped).
// Numerics identical to rounds 4-13 (all passed): spikes exact in i8; W = 5
// balanced base-256 digits of round(w*2^40); x digitized to round(x*2^36)
// (digit pairs p+q>=4); i32 MFMA accumulation exact; cur fp64 (<2^53 exact).
// 32x32x32 C/D layout (m74/m101): col=l&31, row=(reg&3)+8*(reg>>2)+4*(l>>5).
// A/B share the identical lane->k map, so any HW k-permutation cancels.

typedef int int4v  __attribute__((ext_vector_type(4)));
typedef int int16v __attribute__((ext_vector_type(16)));

#define XSCALE 68719476736.0      // 2^36
#define WSCALE 1099511627776.0    // 2^40
#define MT 25600                  // 50 t x 512 batch rows

// ---- W digit split: fp32 [Nreal][K] -> 5 planes [Npad][Kpad], zero-padded ----
__global__ void wsplit_i8(const float* __restrict__ W, signed char* __restrict__ out,
                          int Nreal, int Npad, int K, int Kpad)
{
    int idx = blockIdx.x * blockDim.x + threadIdx.x;
    int total = Npad * Kpad;
    if (idx >= total) return;
    int n = idx / Kpad, k = idx - n * Kpad;
    long long v = 0;
    if (n < Nreal && k < K) v = __double2ll_rn((double)W[(size_t)n * K + k] * WSCALE);
    size_t plane = (size_t)total;
#pragma unroll
    for (int p = 0; p < 4; ++p) {
        int d = (int)(v & 255); if (d > 127) d -= 256;
        out[p * plane + idx] = (signed char)d;
        v = (v - d) >> 8;
    }
    out[4 * plane + idx] = (signed char)v;
}

// ---- x digitize (all 50 t): [25600][784] fp32 -> 5 planes [25600][832] ----
__global__ void xsplit_all(const float* __restrict__ x, signed char* __restrict__ out)
{
    int idx = blockIdx.x * blockDim.x + threadIdx.x;
    if (idx >= MT * 832) return;
    int row = idx / 832, k = idx - row * 832;
    long long v = 0;
    if (k < 784) v = __double2ll_rn((double)x[(size_t)row * 784 + k] * XSCALE);
    const size_t plane = (size_t)MT * 832;
    signed char* o = out + idx;
#pragma unroll
    for (int p = 0; p < 4; ++p) {
        int d = (int)(v & 255); if (d > 127) d -= 256;
        o[p * plane] = (signed char)d;
        v = (v - d) >> 8;
    }
    o[4 * plane] = (signed char)v;
}

// ---- L0/L3 GEMM: block 64x64, 4 waves 2x2, wave 32x32 (round-13 proven) ----
template<int NA, int KP, int CS>
__global__ __launch_bounds__(256)
void gemm32(const signed char* __restrict__ Ap, size_t planeA,
            const signed char* __restrict__ Wp, size_t planeW,
            double* __restrict__ curout)
{
    __shared__ __align__(16) signed char Wld[5 * 64 * 80];
    __shared__ __align__(16) signed char Ald[NA * 64 * 80];
    constexpr int NIT = KP / 64;

    const int tid = threadIdx.x;
    const int l   = tid & 63;
    const int w   = tid >> 6;
    const int wm  = (w & 1) * 32;
    const int wn  = (w >> 1) * 32;
    const int r32 = l & 31;
    const int h   = l >> 5;

    const int bm = blockIdx.y * 64;
    const int bn = blockIdx.x * 64;

    const int srow = tid >> 2;
    const int sc   = (tid & 3) * 16;

    const signed char* ag = Ap + (size_t)(bm + srow) * KP + sc;
    const signed char* wg = Wp + (size_t)(bn + srow) * KP + sc;

    int4v Ar[NA], Wr[5];
#pragma unroll
    for (int p = 0; p < 5; ++p)  Wr[p] = *(const int4v*)(wg + p * planeW);
#pragma unroll
    for (int p = 0; p < NA; ++p) Ar[p] = *(const int4v*)(ag + p * planeA);

    int16v acc[5];
#pragma unroll
    for (int s = 0; s < 5; ++s)
#pragma unroll
        for (int r = 0; r < 16; ++r) acc[s][r] = 0;

    for (int it = 0; it < NIT; ++it) {
        __syncthreads();
#pragma unroll
        for (int p = 0; p < 5; ++p)
            *(int4v*)&Wld[(p * 64 + srow) * 80 + sc] = Wr[p];
#pragma unroll
        for (int p = 0; p < NA; ++p)
            *(int4v*)&Ald[(p * 64 + srow) * 80 + sc] = Ar[p];
        __syncthreads();

        if (it + 1 < NIT) {
            int kb = (it + 1) * 64;
#pragma unroll
            for (int p = 0; p < 5; ++p)
                Wr[p] = *(const int4v*)(wg + kb + p * planeW);
#pragma unroll
            for (int p = 0; p < NA; ++p)
                Ar[p] = *(const int4v*)(ag + kb + p * planeA);
        }

#pragma unroll
        for (int k2 = 0; k2 < 2; ++k2) {
            const int off = k2 * 32 + 16 * h;
            if constexpr (NA == 5) {
                int4v af[5], bq[5];
#pragma unroll
                for (int p = 0; p < 5; ++p)
                    af[p] = *(const int4v*)&Ald[(p * 64 + wm + r32) * 80 + off];
#pragma unroll
                for (int q = 0; q < 5; ++q)
                    bq[q] = *(const int4v*)&Wld[(q * 64 + wn + r32) * 80 + off];
#pragma unroll
                for (int q = 0; q < 5; ++q)
#pragma unroll
                    for (int p = 0; p < 5; ++p)
                        if (p + q >= 4)
                            acc[p + q - 4] = __builtin_amdgcn_mfma_i32_32x32x32_i8(
                                af[p], bq[q], acc[p + q - 4], 0, 0, 0);
            } else {
                int4v a0 = *(const int4v*)&Ald[(wm + r32) * 80 + off];
#pragma unroll
                for (int q = 0; q < 5; ++q) {
                    int4v bq = *(const int4v*)&Wld[(q * 64 + wn + r32) * 80 + off];
                    acc[q] = __builtin_amdgcn_mfma_i32_32x32x32_i8(a0, bq, acc[q], 0, 0, 0);
                }
            }
        }
    }

    const int col = bn + wn + r32;
    if (col < CS) {
#pragma unroll
        for (int reg = 0; reg < 16; ++reg) {
            int row = bm + wm + (reg & 3) + 8 * (reg >> 2) + 4 * h;
            double v = (double)acc[4][reg];
            v = v * 256.0 + (double)acc[3][reg];
            v = v * 256.0 + (double)acc[2][reg];
            v = v * 256.0 + (double)acc[1][reg];
            v = v * 256.0 + (double)acc[0][reg];
            curout[(size_t)row * CS + col] = v * (NA == 5 ? 0x1p-44 : 0x1p-40);
        }
    }
}

// ---- wide spike-layer GEMM, LDS DOUBLE-BUFFERED (one barrier per k-iter) ----
// block 128x64, 4 waves 2x2, wave 64x32 (Mf=2).
template<int KP>
__global__ __launch_bounds__(256)
void gemm32w(const signed char* __restrict__ Asp,
             const signed char* __restrict__ Wp, size_t planeW,
             double* __restrict__ curout)
{
    __shared__ __align__(16) signed char Wld[2][5 * 64 * 80];   // 51.2 KB
    __shared__ __align__(16) signed char Ald[2][128 * 80];      // 20.5 KB
    constexpr int NIT = KP / 64;

    const int tid = threadIdx.x;
    const int l   = tid & 63;
    const int w   = tid >> 6;           // 0..3
    const int wm  = (w & 1) * 64;       // 0/64
    const int wn  = (w >> 1) * 32;      // 0/32
    const int r32 = l & 31;
    const int h   = l >> 5;

    const int bm = blockIdx.y * 128;
    const int bn = blockIdx.x * 64;

    const int srA = tid >> 1;           // 0..127
    const int scA = (tid & 1) * 32;
    const int srW = tid >> 2;           // 0..63
    const int scW = (tid & 3) * 16;

    const signed char* ag = Asp + (size_t)(bm + srA) * KP + scA;
    const signed char* wg = Wp  + (size_t)(bn + srW) * KP + scW;

    // prologue: k0 -> buf0; prefetch k1 into regs
    int4v Ar0 = *(const int4v*)(ag);
    int4v Ar1 = *(const int4v*)(ag + 16);
    int4v Wr[5];
#pragma unroll
    for (int p = 0; p < 5; ++p) Wr[p] = *(const int4v*)(wg + p * planeW);
#pragma unroll
    for (int p = 0; p < 5; ++p)
        *(int4v*)&Wld[0][(p * 64 + srW) * 80 + scW] = Wr[p];
    *(int4v*)&Ald[0][srA * 80 + scA]      = Ar0;
    *(int4v*)&Ald[0][srA * 80 + scA + 16] = Ar1;
    if (NIT > 1) {
        Ar0 = *(const int4v*)(ag + 64);
        Ar1 = *(const int4v*)(ag + 64 + 16);
#pragma unroll
        for (int p = 0; p < 5; ++p)
            Wr[p] = *(const int4v*)(wg + 64 + p * planeW);
    }
    __syncthreads();

    int16v acc[2][5];
#pragma unroll
    for (int mi = 0; mi < 2; ++mi)
#pragma unroll
        for (int s = 0; s < 5; ++s)
#pragma unroll
            for (int r = 0; r < 16; ++r) acc[mi][s][r] = 0;

    for (int it = 0; it < NIT; ++it) {
        const int cur = it & 1;

        // compute from buf[cur]
#pragma unroll
        for (int k2 = 0; k2 < 2; ++k2) {
            const int off = k2 * 32 + 16 * h;
            int4v bq[5];
#pragma unroll
            for (int q = 0; q < 5; ++q)
                bq[q] = *(const int4v*)&Wld[cur][(q * 64 + wn + r32) * 80 + off];
#pragma unroll
            for (int mi = 0; mi < 2; ++mi) {
                int4v a0 = *(const int4v*)&Ald[cur][(wm + mi * 32 + r32) * 80 + off];
#pragma unroll
                for (int q = 0; q < 5; ++q)
                    acc[mi][q] = __builtin_amdgcn_mfma_i32_32x32x32_i8(
                        a0, bq[q], acc[mi][q], 0, 0, 0);
            }
        }

        // stage k=it+1 into buf[cur^1] (overlaps other waves' compute on buf[cur])
        if (it + 1 < NIT) {
            const int nxt = cur ^ 1;
#pragma unroll
            for (int p = 0; p < 5; ++p)
                *(int4v*)&Wld[nxt][(p * 64 + srW) * 80 + scW] = Wr[p];
            *(int4v*)&Ald[nxt][srA * 80 + scA]      = Ar0;
            *(int4v*)&Ald[nxt][srA * 80 + scA + 16] = Ar1;
            if (it + 2 < NIT) {
                int kb = (it + 2) * 64;
                Ar0 = *(const int4v*)(ag + kb);
                Ar1 = *(const int4v*)(ag + kb + 16);
#pragma unroll
                for (int p = 0; p < 5; ++p)
                    Wr[p] = *(const int4v*)(wg + kb + p * planeW);
            }
            __syncthreads();   // single barrier per iteration
        }
    }

    const int col = bn + wn + r32;
#pragma unroll
    for (int mi = 0; mi < 2; ++mi)
#pragma unroll
        for (int reg = 0; reg < 16; ++reg) {
            int row = bm + wm + mi * 32 + (reg & 3) + 8 * (reg >> 2) + 4 * h;
            double v = (double)acc[mi][4][reg];
            v = v * 256.0 + (double)acc[mi][3][reg];
            v = v * 256.0 + (double)acc[mi][2][reg];
            v = v * 256.0 + (double)acc[mi][1][reg];
            v = v * 256.0 + (double)acc[mi][0][reg];
            curout[(size_t)row * 1024 + col] = v * 0x1p-40;
        }
}

// ---- leaky-IF over ALL 50 t, 2 cols/thread; covers K-tail (zeroes spk_i8) ----
__global__ __launch_bounds__(256)
void if_update(const double* __restrict__ cur, const float* __restrict__ bias,
               float* __restrict__ spk, float* __restrict__ mem,
               signed char* __restrict__ spk_i8)
{
    int idx = blockIdx.x * blockDim.x + threadIdx.x;     // 512 rows x 512 col-pairs
    if (idx >= 512 * 512) return;
    int row = idx >> 9, col = (idx & 511) * 2;
    if (col >= 1000) {                                   // K-tail: keep zeros
        for (int t = 0; t < 50; ++t)
            *(short*)&spk_i8[((size_t)t * 512 + row) * 1024 + col] = 0;
        return;
    }
    double mp0 = 0.0, mp1 = 0.0;
    double bs0 = (double)bias[col], bs1 = (double)bias[col + 1];
    for (int t = 0; t < 50; ++t) {
        double2 c = *(const double2*)&cur[((size_t)t * 512 + row) * 1024 + col];
        double rst0 = (mp0 > 1.0) ? 1.0 : 0.0;
        double rst1 = (mp1 > 1.0) ? 1.0 : 0.0;
        double mn0 = 0.9 * mp0 + (c.x + bs0) - rst0;
        double mn1 = 0.9 * mp1 + (c.y + bs1) - rst1;
        int s0 = (mn0 > 1.0) ? 1 : 0;
        int s1 = (mn1 > 1.0) ? 1 : 0;
        size_t o = ((size_t)t * 512 + row) * 1000 + col;
        *(float2*)&spk[o] = make_float2((float)s0, (float)s1);
        *(float2*)&mem[o] = make_float2((float)mn0, (float)mn1);
        *(short*)&spk_i8[((size_t)t * 512 + row) * 1024 + col] =
            (short)(s0 | (s1 << 8));
        mp0 = mn0; mp1 = mn1;
    }
}

// ---- layer-3 IF chain: 5120 neurons, all 50 t in registers ----
__global__ __launch_bounds__(256)
void if3_kernel(const double* __restrict__ cur3, const float* __restrict__ bias,
                float* __restrict__ spk3, float* __restrict__ mem3)
{
    int idx = blockIdx.x * blockDim.x + threadIdx.x;
    if (idx >= 5120) return;
    int brow = idx / 10, col = idx - brow * 10;
    double bs = (double)bias[col];
    double mp = 0.0;
    for (int t = 0; t < 50; ++t) {
        double c   = cur3[((size_t)t * 512 + brow) * 16 + col] + bs;
        double rst = (mp > 1.0) ? 1.0 : 0.0;
        double mn  = 0.9 * mp + c - rst;
        size_t o   = (size_t)t * 5120 + (size_t)brow * 10 + col;
        spk3[o] = (mn > 1.0) ? 1.0f : 0.0f;
        mem3[o] = (float)mn;
        mp = mn;
    }
}

extern "C" void kernel_launch(void* const* d_in, const int* in_sizes, int n_in,
                              void* d_out, int out_size, void* d_ws, size_t ws_size,
                              hipStream_t stream)
{
    const float* x  = (const float*)d_in[0];
    const float* W0 = (const float*)d_in[1];
    const float* b0 = (const float*)d_in[2];
    const float* W1 = (const float*)d_in[3];
    const float* b1 = (const float*)d_in[4];
    const float* W2 = (const float*)d_in[5];
    const float* b2 = (const float*)d_in[6];
    const float* W3 = (const float*)d_in[7];
    const float* b3 = (const float*)d_in[8];
    float* out = (float*)d_out;

    const int T = 50;
    const size_t LNH = (size_t)512 * 1000;
    const size_t LNO = (size_t)512 * 10;

    float* spk0 = out;
    float* spk1 = spk0 + (size_t)T * LNH;
    float* spk2 = spk1 + (size_t)T * LNH;
    float* spk3 = spk2 + (size_t)T * LNH;
    float* mem0 = spk3 + (size_t)T * LNO;
    float* mem1 = mem0 + (size_t)T * LNH;
    float* mem2 = mem1 + (size_t)T * LNH;
    float* mem3 = mem2 + (size_t)T * LNH;

    // ---- workspace layout (fp64 first, then i8); total ~410 MB ----
    double* cur = (double*)d_ws;                          // 25600*1024*8 = 210 MB
    signed char* W0d = (signed char*)(cur + (size_t)MT * 1024);   // 5*1024*832
    signed char* W1d = W0d + (size_t)5 * 1024 * 832;      // 5*1024*1024
    signed char* W2d = W1d + (size_t)5 * 1024 * 1024;
    signed char* W3d = W2d + (size_t)5 * 1024 * 1024;     // 5*64*1024
    signed char* xsb = W3d + (size_t)5 * 64 * 1024;       // 5*25600*832 = 106.5 MB
    signed char* sp0 = xsb + (size_t)5 * MT * 832;        // 25600*1024 = 26.2 MB
    signed char* sp1 = sp0 + (size_t)MT * 1024;
    signed char* sp2 = sp1 + (size_t)MT * 1024;

    // W digit splits
    wsplit_i8<<<(1024 * 832  + 255) / 256, 256, 0, stream>>>(W0, W0d, 1000, 1024, 784,  832);
    wsplit_i8<<<(1024 * 1024 + 255) / 256, 256, 0, stream>>>(W1, W1d, 1000, 1024, 1000, 1024);
    wsplit_i8<<<(1024 * 1024 + 255) / 256, 256, 0, stream>>>(W2, W2d, 1000, 1024, 1000, 1024);
    wsplit_i8<<<(64 * 1024   + 255) / 256, 256, 0, stream>>>(W3, W3d, 10,   64,   1000, 1024);

    // x digitize, all 50 t
    xsplit_all<<<(MT * 832 + 255) / 256, 256, 0, stream>>>(x, xsb);

    const size_t plA0 = (size_t)MT * 832;
    const size_t plW0 = (size_t)1024 * 832;
    const size_t plWH = (size_t)1024 * 1024;
    const size_t plW3 = (size_t)64 * 1024;

    dim3 blk(256);
    dim3 g0(16, MT / 64);     // L0: 64x64 tiles  -> 6400 blocks
    dim3 gW(16, MT / 128);    // L1/L2: 128x64    -> 3200 blocks
    dim3 g3(1, MT / 64);      // L3: 64x64, N=16  -> 400 blocks

    // L0
    gemm32<5, 832, 1024><<<g0, blk, 0, stream>>>(xsb, plA0, W0d, plW0, cur);
    if_update<<<1024, 256, 0, stream>>>(cur, b0, spk0, mem0, sp0);
    // L1
    gemm32w<1024><<<gW, blk, 0, stream>>>(sp0, W1d, plWH, cur);
    if_update<<<1024, 256, 0, stream>>>(cur, b1, spk1, mem1, sp1);
    // L2
    gemm32w<1024><<<gW, blk, 0, stream>>>(sp1, W2d, plWH, cur);
    if_update<<<1024, 256, 0, stream>>>(cur, b2, spk2, mem2, sp2);
    // L3
    gemm32<1, 1024, 16><<<g3, blk, 0, stream>>>(sp2, 0, W3d, plW3, cur);
    if3_kernel<<<20, 256, 0, stream>>>(cur, b3, spk3, mem3);
}